// Round 2
// baseline (1560.839 us; speedup 1.0000x reference)
//
#include <hip/hip_runtime.h>

// ---------------------------------------------------------------------------
// SimpleEquivariantNetwork: 3-layer equivariant message passing.
// Decomposition:
//   K0 edge_pre : per-edge SH attrs [E,4] + folded radial scalars c[3,E]
//   K1 embed    : h = x @ W_embed                        [N,32]
//   per layer l: K2 tp_gemm : Hp = h @ W_tp[l]           [N,128]  (node-side TP)
//                K3 scatter : h[dst] += c * (attr . Hp[src])  (atomic, fused residual)
//   K4 pool     : gsum/cnt by batch (atomics; batch sorted -> low contention)
//   K5 final    : decode + orientation SH dot            [G]
// ---------------------------------------------------------------------------

constexpr int Dk  = 32;   // feature dim D
constexpr int Ak  = 4;    // SH components (lmax=1)
constexpr int Hk  = 64;   // radial hidden
constexpr int NBk = 10;   // radial basis
constexpr int Lk  = 3;    // layers
constexpr int FinK = 16;  // input features

__device__ __forceinline__ float sus(float x) {
    // exp(-1/x) for x>0 else 0
    return x > 0.f ? __expf(-1.f / x) : 0.f;
}

__global__ __launch_bounds__(256) void edge_pre(
    const float* __restrict__ pos, const int* __restrict__ esrc,
    const int* __restrict__ edst,
    const float* __restrict__ Wfc1,  // [3,10,64]
    const float* __restrict__ Wfc2,  // [3,64,1]
    float4* __restrict__ attr,       // [E]
    float* __restrict__ cfac,        // [3,E]
    int E)
{
    __shared__ float sW1[Lk * NBk * Hk];  // 1920 floats
    __shared__ float sW2[Lk * Hk];        // 192 floats
    for (int i = threadIdx.x; i < Lk * NBk * Hk; i += blockDim.x) sW1[i] = Wfc1[i];
    for (int i = threadIdx.x; i < Lk * Hk; i += blockDim.x) sW2[i] = Wfc2[i];
    __syncthreads();

    int e = blockIdx.x * blockDim.x + threadIdx.x;
    if (e >= E) return;
    int s = esrc[e], d = edst[e];
    float vx = pos[3 * s + 0] - pos[3 * d + 0];
    float vy = pos[3 * s + 1] - pos[3 * d + 1];
    float vz = pos[3 * s + 2] - pos[3 * d + 2];
    float len = sqrtf(vx * vx + vy * vy + vz * vz);
    float inv = 1.f / (len + 1e-9f);
    const float S3 = 1.7320508075688772f;
    attr[e] = make_float4(1.f, S3 * vy * inv, S3 * vz * inv, S3 * vx * inv);

    // soft_one_hot 'smooth_finite', knots v_j = 5(j+1)/11, step 5/11.
    // Folded: SMOOTH_C * sqrt(10) * fc1_norm = SMOOTH_C (since sqrt(10)*1/sqrt(10)=1)
    const float C_EMB = (float)(1.14136 * 7.3890560989306495);
    float t = len * 2.2f;  // len/step
    float emb[NBk];
#pragma unroll
    for (int j = 0; j < NBk; j++) {
        float d1 = t - (float)j;        // diff + 1
        float d2 = (float)(j + 2) - t;  // 1 - diff
        emb[j] = C_EMB * sus(d1) * sus(d2);
    }

    // c = rad * fc2_norm * tp_norm * agg_norm
    const float C_OUT = (float)(0.125 * 0.08838834764831845 * 0.2581988897471611);
#pragma unroll
    for (int l = 0; l < Lk; l++) {
        const float* w1 = &sW1[l * NBk * Hk];
        const float* w2 = &sW2[l * Hk];
        float r = 0.f;
        for (int j = 0; j < Hk; j++) {
            float a = 0.f;
#pragma unroll
            for (int b = 0; b < NBk; b++) a += emb[b] * w1[b * Hk + j];
            float sg = 1.f / (1.f + __expf(-a));  // silu(a) = a*sigmoid(a)
            r += a * sg * w2[j];
        }
        cfac[(size_t)l * E + e] = r * C_OUT;
    }
}

__global__ __launch_bounds__(256) void embed_k(
    const float* __restrict__ x, const float* __restrict__ We,
    float* __restrict__ h, int N)
{
    __shared__ float sW[FinK * Dk];  // 512
    for (int i = threadIdx.x; i < FinK * Dk; i += blockDim.x) sW[i] = We[i];
    __syncthreads();
    int tid = blockIdx.x * blockDim.x + threadIdx.x;
    int n = tid >> 5, k = tid & 31;
    if (n >= N) return;
    float acc = 0.f;
#pragma unroll
    for (int i = 0; i < FinK; i++) acc += x[n * FinK + i] * sW[i * Dk + k];
    h[n * Dk + k] = acc;
}

__global__ __launch_bounds__(256) void tp_gemm(
    const float* __restrict__ h, const float* __restrict__ Wl,  // [32,4,32]
    float* __restrict__ Hp, int N)
{
    int tid = blockIdx.x * blockDim.x + threadIdx.x;
    int n = tid >> 5, k = tid & 31;
    if (n >= N) return;
    float hv = h[(size_t)n * Dk + k];
    float a0 = 0.f, a1 = 0.f, a2 = 0.f, a3 = 0.f;
#pragma unroll
    for (int i = 0; i < Dk; i++) {
        float hb = __shfl(hv, i, 32);
        a0 += hb * Wl[i * 128 + 0 * 32 + k];
        a1 += hb * Wl[i * 128 + 1 * 32 + k];
        a2 += hb * Wl[i * 128 + 2 * 32 + k];
        a3 += hb * Wl[i * 128 + 3 * 32 + k];
    }
    float* o = Hp + (size_t)n * 128;
    o[k] = a0; o[32 + k] = a1; o[64 + k] = a2; o[96 + k] = a3;
}

__global__ __launch_bounds__(256) void edge_scatter(
    const float* __restrict__ Hp, const float4* __restrict__ attr,
    const float* __restrict__ cl, const int* __restrict__ esrc,
    const int* __restrict__ edst, float* __restrict__ h, int E)
{
    int tid = blockIdx.x * blockDim.x + threadIdx.x;
    int e = tid >> 5, k = tid & 31;
    if (e >= E) return;
    int s = esrc[e], d = edst[e];
    float4 a = attr[e];
    float c = cl[e];
    const float* hp = Hp + (size_t)s * 128;
    float v = a.x * hp[k] + a.y * hp[32 + k] + a.z * hp[64 + k] + a.w * hp[96 + k];
    unsafeAtomicAdd(&h[(size_t)d * Dk + k], c * v);
}

__global__ __launch_bounds__(256) void pool_k(
    const float* __restrict__ h, const int* __restrict__ batch,
    float* __restrict__ gsum, float* __restrict__ cnt, int N)
{
    int tid = blockIdx.x * blockDim.x + threadIdx.x;
    int n = tid >> 5, k = tid & 31;
    if (n >= N) return;
    int g = batch[n];
    unsafeAtomicAdd(&gsum[g * Dk + k], h[(size_t)n * Dk + k]);
    if (k == 0) unsafeAtomicAdd(&cnt[g], 1.0f);
}

__global__ __launch_bounds__(64) void final_k(
    const float* __restrict__ gsum, const float* __restrict__ cnt,
    const float* __restrict__ Wdec,   // [32,4]
    const float* __restrict__ orient, // [G,2]
    float* __restrict__ out, int G)
{
    int g = blockIdx.x * blockDim.x + threadIdx.x;
    if (g >= G) return;
    float ic = 1.f / fmaxf(cnt[g], 1.f);
    float c0 = 0.f, c1 = 0.f, c2 = 0.f, c3 = 0.f;
#pragma unroll
    for (int i = 0; i < Dk; i++) {
        float gv = gsum[g * Dk + i] * ic;
        c0 += gv * Wdec[i * 4 + 0];
        c1 += gv * Wdec[i * 4 + 1];
        c2 += gv * Wdec[i * 4 + 2];
        c3 += gv * Wdec[i * 4 + 3];
    }
    float th = orient[g * 2 + 0], ph = orient[g * 2 + 1];
    float st = sinf(th), ct = cosf(th), sp = sinf(ph), cp = cosf(ph);
    float qx = st * cp, qy = st * sp, qz = ct;
    const float S3 = 1.7320508075688772f;
    out[g] = c0 + c1 * S3 * qy + c2 * S3 * qz + c3 * S3 * qx;
}

extern "C" void kernel_launch(void* const* d_in, const int* in_sizes, int n_in,
                              void* d_out, int out_size, void* d_ws, size_t ws_size,
                              hipStream_t stream) {
    const float* pos     = (const float*)d_in[0];
    const float* x       = (const float*)d_in[1];
    const float* orient  = (const float*)d_in[2];
    const float* W_embed = (const float*)d_in[3];
    const float* W_tp    = (const float*)d_in[4];
    const float* W_fc1   = (const float*)d_in[5];
    const float* W_fc2   = (const float*)d_in[6];
    const float* W_dec   = (const float*)d_in[7];
    const int*   esrc    = (const int*)d_in[8];
    const int*   edst    = (const int*)d_in[9];
    const int*   batch   = (const int*)d_in[10];

    const int N = in_sizes[0] / 3;
    const int E = in_sizes[8];
    const int G = in_sizes[2] / 2;

    // workspace layout (floats): attr[4E] | cfac[3E] | h[32N] | Hp[128N] | gsum[32G] | cnt[G]
    float*  ws   = (float*)d_ws;
    float4* attr = (float4*)ws;
    float*  cfac = ws + (size_t)4 * E;
    float*  h    = cfac + (size_t)3 * E;
    float*  Hp   = h + (size_t)Dk * N;
    float*  gsum = Hp + (size_t)128 * N;
    float*  cnt  = gsum + (size_t)Dk * G;

    hipMemsetAsync(gsum, 0, (size_t)(Dk * G + G) * sizeof(float), stream);

    edge_pre<<<(E + 255) / 256, 256, 0, stream>>>(pos, esrc, edst, W_fc1, W_fc2, attr, cfac, E);
    embed_k<<<(N * 32 + 255) / 256, 256, 0, stream>>>(x, W_embed, h, N);

    for (int l = 0; l < Lk; l++) {
        tp_gemm<<<(N * 32 + 255) / 256, 256, 0, stream>>>(
            h, W_tp + (size_t)l * Dk * Ak * Dk, Hp, N);
        edge_scatter<<<(int)(((size_t)E * 32 + 255) / 256), 256, 0, stream>>>(
            Hp, attr, cfac + (size_t)l * E, esrc, edst, h, E);
    }

    pool_k<<<(N * 32 + 255) / 256, 256, 0, stream>>>(h, batch, gsum, cnt, N);
    final_k<<<(G + 63) / 64, 64, 0, stream>>>(gsum, cnt, W_dec, orient, (float*)d_out, G);
}

// Round 4
// 700.846 us; speedup vs baseline: 2.2271x; 2.2271x over previous
//
#include <hip/hip_runtime.h>

// ---------------------------------------------------------------------------
// SimpleEquivariantNetwork: 3-layer equivariant message passing.
//   K0 edge_pre : per-edge SH attrs [E,4] + folded radial scalars c[3,E]
//   K1 embed    : h = x @ W_embed                        [N,32]
//   per layer l: K2 tp_gemm : Hp = h @ W_tp[l]           [N,128]  (node-side TP)
//                K3 scatter : h[dst] += c * (attr . Hp[src])  (atomic, fused residual)
//   K4 pool     : register-accumulated segment sum (batch sorted -> ~2 flushes/thread)
//   K5 final    : decode + orientation SH dot            [G]
// ---------------------------------------------------------------------------

constexpr int Dk  = 32;   // feature dim D
constexpr int Ak  = 4;    // SH components (lmax=1)
constexpr int Hk  = 64;   // radial hidden
constexpr int NBk = 10;   // radial basis
constexpr int Lk  = 3;    // layers
constexpr int FinK = 16;  // input features

__device__ __forceinline__ float sus(float x) {
    // exp(-1/x) for x>0 else 0
    return x > 0.f ? __expf(-1.f / x) : 0.f;
}

__global__ __launch_bounds__(256) void edge_pre(
    const float* __restrict__ pos, const int* __restrict__ esrc,
    const int* __restrict__ edst,
    const float* __restrict__ Wfc1,  // [3,10,64]
    const float* __restrict__ Wfc2,  // [3,64,1]
    float4* __restrict__ attr,       // [E]
    float* __restrict__ cfac,        // [3,E]
    int E)
{
    __shared__ float sW1[Lk * NBk * Hk];  // 1920 floats
    __shared__ float sW2[Lk * Hk];        // 192 floats
    for (int i = threadIdx.x; i < Lk * NBk * Hk; i += blockDim.x) sW1[i] = Wfc1[i];
    for (int i = threadIdx.x; i < Lk * Hk; i += blockDim.x) sW2[i] = Wfc2[i];
    __syncthreads();

    int e = blockIdx.x * blockDim.x + threadIdx.x;
    if (e >= E) return;
    int s = esrc[e], d = edst[e];
    float vx = pos[3 * s + 0] - pos[3 * d + 0];
    float vy = pos[3 * s + 1] - pos[3 * d + 1];
    float vz = pos[3 * s + 2] - pos[3 * d + 2];
    float len = sqrtf(vx * vx + vy * vy + vz * vz);
    float inv = 1.f / (len + 1e-9f);
    const float S3 = 1.7320508075688772f;
    attr[e] = make_float4(1.f, S3 * vy * inv, S3 * vz * inv, S3 * vx * inv);

    // soft_one_hot 'smooth_finite', knots v_j = 5(j+1)/11, step 5/11.
    // Folded: SMOOTH_C * sqrt(10) * fc1_norm = SMOOTH_C (since sqrt(10)*1/sqrt(10)=1)
    const float C_EMB = (float)(1.14136 * 7.3890560989306495);
    float t = len * 2.2f;  // len/step
    float emb[NBk];
#pragma unroll
    for (int j = 0; j < NBk; j++) {
        float d1 = t - (float)j;        // diff + 1
        float d2 = (float)(j + 2) - t;  // 1 - diff
        emb[j] = C_EMB * sus(d1) * sus(d2);
    }

    // c = rad * fc2_norm * tp_norm * agg_norm
    const float C_OUT = (float)(0.125 * 0.08838834764831845 * 0.2581988897471611);
#pragma unroll
    for (int l = 0; l < Lk; l++) {
        const float* w1 = &sW1[l * NBk * Hk];
        const float* w2 = &sW2[l * Hk];
        float r = 0.f;
        for (int j = 0; j < Hk; j++) {
            float a = 0.f;
#pragma unroll
            for (int b = 0; b < NBk; b++) a += emb[b] * w1[b * Hk + j];
            float sg = 1.f / (1.f + __expf(-a));  // silu(a) = a*sigmoid(a)
            r += a * sg * w2[j];
        }
        cfac[(size_t)l * E + e] = r * C_OUT;
    }
}

__global__ __launch_bounds__(256) void embed_k(
    const float* __restrict__ x, const float* __restrict__ We,
    float* __restrict__ h, int N)
{
    __shared__ float sW[FinK * Dk];  // 512
    for (int i = threadIdx.x; i < FinK * Dk; i += blockDim.x) sW[i] = We[i];
    __syncthreads();
    int tid = blockIdx.x * blockDim.x + threadIdx.x;
    int n = tid >> 5, k = tid & 31;
    if (n >= N) return;
    float acc = 0.f;
#pragma unroll
    for (int i = 0; i < FinK; i++) acc += x[n * FinK + i] * sW[i * Dk + k];
    h[n * Dk + k] = acc;
}

__global__ __launch_bounds__(256) void tp_gemm(
    const float* __restrict__ h, const float* __restrict__ Wl,  // [32,4,32]
    float* __restrict__ Hp, int N)
{
    int tid = blockIdx.x * blockDim.x + threadIdx.x;
    int n = tid >> 5, k = tid & 31;
    if (n >= N) return;
    float hv = h[(size_t)n * Dk + k];
    float a0 = 0.f, a1 = 0.f, a2 = 0.f, a3 = 0.f;
#pragma unroll
    for (int i = 0; i < Dk; i++) {
        float hb = __shfl(hv, i, 32);
        a0 += hb * Wl[i * 128 + 0 * 32 + k];
        a1 += hb * Wl[i * 128 + 1 * 32 + k];
        a2 += hb * Wl[i * 128 + 2 * 32 + k];
        a3 += hb * Wl[i * 128 + 3 * 32 + k];
    }
    float* o = Hp + (size_t)n * 128;
    o[k] = a0; o[32 + k] = a1; o[64 + k] = a2; o[96 + k] = a3;
}

__global__ __launch_bounds__(256) void edge_scatter(
    const float* __restrict__ Hp, const float4* __restrict__ attr,
    const float* __restrict__ cl, const int* __restrict__ esrc,
    const int* __restrict__ edst, float* __restrict__ h, int E)
{
    int tid = blockIdx.x * blockDim.x + threadIdx.x;
    int e = tid >> 5, k = tid & 31;
    if (e >= E) return;
    int s = esrc[e], d = edst[e];
    float4 a = attr[e];
    float c = cl[e];
    const float* hp = Hp + (size_t)s * 128;
    float v = a.x * hp[k] + a.y * hp[32 + k] + a.z * hp[64 + k] + a.w * hp[96 + k];
    unsafeAtomicAdd(&h[(size_t)d * Dk + k], c * v);
}

// Register-accumulated segment sum over sorted `batch`.
// Each thread walks nodes {start+row, +8, ...}; flushes only on g-change.
constexpr int POOL_NPB = 512;  // nodes per block
__global__ __launch_bounds__(256) void pool_k(
    const float* __restrict__ h, const int* __restrict__ batch,
    float* __restrict__ gsum, float* __restrict__ cnt, int N)
{
    int k = threadIdx.x & 31;
    int row = threadIdx.x >> 5;  // 0..7
    int start = blockIdx.x * POOL_NPB;
    int end = min(start + POOL_NPB, N);
    int curg = -1;
    float acc = 0.f, cacc = 0.f;
    for (int n = start + row; n < end; n += 8) {
        int g = batch[n];
        float v = h[(size_t)n * Dk + k];
        if (g != curg) {
            if (curg >= 0) {
                unsafeAtomicAdd(&gsum[curg * Dk + k], acc);
                if (k == 0) unsafeAtomicAdd(&cnt[curg], cacc);
            }
            curg = g; acc = 0.f; cacc = 0.f;
        }
        acc += v; cacc += 1.f;
    }
    if (curg >= 0) {
        unsafeAtomicAdd(&gsum[curg * Dk + k], acc);
        if (k == 0) unsafeAtomicAdd(&cnt[curg], cacc);
    }
}

__global__ __launch_bounds__(64) void final_k(
    const float* __restrict__ gsum, const float* __restrict__ cnt,
    const float* __restrict__ Wdec,   // [32,4]
    const float* __restrict__ orient, // [G,2]
    float* __restrict__ out, int G)
{
    int g = blockIdx.x * blockDim.x + threadIdx.x;
    if (g >= G) return;
    float ic = 1.f / fmaxf(cnt[g], 1.f);
    float c0 = 0.f, c1 = 0.f, c2 = 0.f, c3 = 0.f;
#pragma unroll
    for (int i = 0; i < Dk; i++) {
        float gv = gsum[g * Dk + i] * ic;
        c0 += gv * Wdec[i * 4 + 0];
        c1 += gv * Wdec[i * 4 + 1];
        c2 += gv * Wdec[i * 4 + 2];
        c3 += gv * Wdec[i * 4 + 3];
    }
    float th = orient[g * 2 + 0], ph = orient[g * 2 + 1];
    float st = sinf(th), ct = cosf(th), sp = sinf(ph), cp = cosf(ph);
    float qx = st * cp, qy = st * sp, qz = ct;
    const float S3 = 1.7320508075688772f;
    out[g] = c0 + c1 * S3 * qy + c2 * S3 * qz + c3 * S3 * qx;
}

extern "C" void kernel_launch(void* const* d_in, const int* in_sizes, int n_in,
                              void* d_out, int out_size, void* d_ws, size_t ws_size,
                              hipStream_t stream) {
    const float* pos     = (const float*)d_in[0];
    const float* x       = (const float*)d_in[1];
    const float* orient  = (const float*)d_in[2];
    const float* W_embed = (const float*)d_in[3];
    const float* W_tp    = (const float*)d_in[4];
    const float* W_fc1   = (const float*)d_in[5];
    const float* W_fc2   = (const float*)d_in[6];
    const float* W_dec   = (const float*)d_in[7];
    const int*   esrc    = (const int*)d_in[8];
    const int*   edst    = (const int*)d_in[9];
    const int*   batch   = (const int*)d_in[10];

    const int N = in_sizes[0] / 3;
    const int E = in_sizes[8];
    const int G = in_sizes[2] / 2;

    // workspace layout (floats): attr[4E] | cfac[3E] | h[32N] | Hp[128N] | gsum[32G] | cnt[G]
    float*  ws   = (float*)d_ws;
    float4* attr = (float4*)ws;
    float*  cfac = ws + (size_t)4 * E;
    float*  h    = cfac + (size_t)3 * E;
    float*  Hp   = h + (size_t)Dk * N;
    float*  gsum = Hp + (size_t)128 * N;
    float*  cnt  = gsum + (size_t)Dk * G;

    hipMemsetAsync(gsum, 0, (size_t)(Dk * G + G) * sizeof(float), stream);

    edge_pre<<<(E + 255) / 256, 256, 0, stream>>>(pos, esrc, edst, W_fc1, W_fc2, attr, cfac, E);
    embed_k<<<(N * 32 + 255) / 256, 256, 0, stream>>>(x, W_embed, h, N);

    for (int l = 0; l < Lk; l++) {
        tp_gemm<<<(N * 32 + 255) / 256, 256, 0, stream>>>(
            h, W_tp + (size_t)l * Dk * Ak * Dk, Hp, N);
        edge_scatter<<<(int)(((size_t)E * 32 + 255) / 256), 256, 0, stream>>>(
            Hp, attr, cfac + (size_t)l * E, esrc, edst, h, E);
    }

    pool_k<<<(N + POOL_NPB - 1) / POOL_NPB, 256, 0, stream>>>(h, batch, gsum, cnt, N);
    final_k<<<(G + 63) / 64, 64, 0, stream>>>(gsum, cnt, W_dec, orient, (float*)d_out, G);
}

// Round 5
// 562.809 us; speedup vs baseline: 2.7733x; 1.2453x over previous
//
#include <hip/hip_runtime.h>

// ---------------------------------------------------------------------------
// SimpleEquivariantNetwork: 3-layer equivariant message passing.
//   K-1 radial_tab : tabulate r_l(len) on 8193-pt grid (radial MLP, 3 layers)
//   K0 edge_pre : per-edge SH attrs [E,4] + table-interp radial scalars c[3,E]
//   K1 embed    : h = x @ W_embed                        [N,32]
//   per layer l: K2 tp_gemm : Hp = h @ W_tp[l]           [N,128]  (node-side TP)
//                K3 scatter : h[dst] += c * (attr . Hp[src])  (atomic, fused residual)
//   K4 pool     : register-accumulated segment sum (batch sorted)
//   K5 final    : decode + orientation SH dot            [G]
// ---------------------------------------------------------------------------

constexpr int Dk  = 32;   // feature dim D
constexpr int Ak  = 4;    // SH components (lmax=1)
constexpr int Hk  = 64;   // radial hidden
constexpr int NBk = 10;   // radial basis
constexpr int Lk  = 3;    // layers
constexpr int FinK = 16;  // input features
constexpr int TAB = 8192; // radial table intervals over [0,5]

__device__ __forceinline__ float sus(float x) {
    // exp(-1/x) for x>0 else 0
    return x > 0.f ? __expf(-1.f / x) : 0.f;
}

// Tabulate the folded radial response r_l(len)*C_OUT at len = 5*i/TAB, i=0..TAB.
__global__ __launch_bounds__(256) void radial_tab_k(
    const float* __restrict__ Wfc1,  // [3,10,64]
    const float* __restrict__ Wfc2,  // [3,64,1]
    float* __restrict__ rtab)        // [3, TAB+1]
{
    int l = blockIdx.y;
    __shared__ float sW1[NBk * Hk];
    __shared__ float sW2[Hk];
    for (int j = threadIdx.x; j < NBk * Hk; j += blockDim.x) sW1[j] = Wfc1[l * NBk * Hk + j];
    for (int j = threadIdx.x; j < Hk; j += blockDim.x) sW2[j] = Wfc2[l * Hk + j];
    __syncthreads();

    int i = blockIdx.x * blockDim.x + threadIdx.x;
    if (i > TAB) return;
    float len = 5.f * (float)i / (float)TAB;

    // soft_one_hot 'smooth_finite'; SMOOTH_C * sqrt(10) * fc1_norm = SMOOTH_C
    const float C_EMB = (float)(1.14136 * 7.3890560989306495);
    float t = len * 2.2f;  // len/step, step = 5/11
    float emb[NBk];
#pragma unroll
    for (int j = 0; j < NBk; j++) {
        float d1 = t - (float)j;        // diff + 1
        float d2 = (float)(j + 2) - t;  // 1 - diff
        emb[j] = C_EMB * sus(d1) * sus(d2);
    }

    // r = sum_j silu(emb . w1[:,j]) * w2[j];  c = r * fc2_norm*tp_norm*agg_norm
    const float C_OUT = (float)(0.125 * 0.08838834764831845 * 0.2581988897471611);
    float r = 0.f;
    for (int j = 0; j < Hk; j++) {
        float a = 0.f;
#pragma unroll
        for (int b = 0; b < NBk; b++) a += emb[b] * sW1[b * Hk + j];
        float sg = 1.f / (1.f + __expf(-a));
        r += a * sg * sW2[j];
    }
    rtab[l * (TAB + 1) + i] = r * C_OUT;
}

__global__ __launch_bounds__(256) void edge_pre(
    const float* __restrict__ pos, const int* __restrict__ esrc,
    const int* __restrict__ edst,
    const float* __restrict__ rtab,  // [3, TAB+1]
    float4* __restrict__ attr,       // [E]
    float* __restrict__ cfac,        // [3,E]
    int E)
{
    int e = blockIdx.x * blockDim.x + threadIdx.x;
    if (e >= E) return;
    int s = esrc[e], d = edst[e];
    float vx = pos[3 * s + 0] - pos[3 * d + 0];
    float vy = pos[3 * s + 1] - pos[3 * d + 1];
    float vz = pos[3 * s + 2] - pos[3 * d + 2];
    float len = sqrtf(vx * vx + vy * vy + vz * vz);
    float inv = 1.f / (len + 1e-9f);
    const float S3 = 1.7320508075688772f;
    attr[e] = make_float4(1.f, S3 * vy * inv, S3 * vz * inv, S3 * vx * inv);

    // table interp; r(len>=5) == 0 exactly, clamp hits that.
    float xx = fminf(len * ((float)TAB / 5.f), (float)TAB);
    int i = min((int)xx, TAB - 1);
    float f = xx - (float)i;
#pragma unroll
    for (int l = 0; l < Lk; l++) {
        float a = rtab[l * (TAB + 1) + i];
        float b = rtab[l * (TAB + 1) + i + 1];
        cfac[(size_t)l * E + e] = a + (b - a) * f;
    }
}

__global__ __launch_bounds__(256) void embed_k(
    const float* __restrict__ x, const float* __restrict__ We,
    float* __restrict__ h, int N)
{
    __shared__ float sW[FinK * Dk];  // 512
    for (int i = threadIdx.x; i < FinK * Dk; i += blockDim.x) sW[i] = We[i];
    __syncthreads();
    int tid = blockIdx.x * blockDim.x + threadIdx.x;
    int n = tid >> 5, k = tid & 31;
    if (n >= N) return;
    float acc = 0.f;
#pragma unroll
    for (int i = 0; i < FinK; i++) acc += x[n * FinK + i] * sW[i * Dk + k];
    h[n * Dk + k] = acc;
}

__global__ __launch_bounds__(256) void tp_gemm(
    const float* __restrict__ h, const float* __restrict__ Wl,  // [32,4,32]
    float* __restrict__ Hp, int N)
{
    int tid = blockIdx.x * blockDim.x + threadIdx.x;
    int n = tid >> 5, k = tid & 31;
    if (n >= N) return;
    float hv = h[(size_t)n * Dk + k];
    float a0 = 0.f, a1 = 0.f, a2 = 0.f, a3 = 0.f;
#pragma unroll
    for (int i = 0; i < Dk; i++) {
        float hb = __shfl(hv, i, 32);
        a0 += hb * Wl[i * 128 + 0 * 32 + k];
        a1 += hb * Wl[i * 128 + 1 * 32 + k];
        a2 += hb * Wl[i * 128 + 2 * 32 + k];
        a3 += hb * Wl[i * 128 + 3 * 32 + k];
    }
    float* o = Hp + (size_t)n * 128;
    o[k] = a0; o[32 + k] = a1; o[64 + k] = a2; o[96 + k] = a3;
}

__global__ __launch_bounds__(256) void edge_scatter(
    const float* __restrict__ Hp, const float4* __restrict__ attr,
    const float* __restrict__ cl, const int* __restrict__ esrc,
    const int* __restrict__ edst, float* __restrict__ h, int E)
{
    int tid = blockIdx.x * blockDim.x + threadIdx.x;
    int e = tid >> 5, k = tid & 31;
    if (e >= E) return;
    int s = esrc[e], d = edst[e];
    float4 a = attr[e];
    float c = cl[e];
    const float* hp = Hp + (size_t)s * 128;
    float v = a.x * hp[k] + a.y * hp[32 + k] + a.z * hp[64 + k] + a.w * hp[96 + k];
    unsafeAtomicAdd(&h[(size_t)d * Dk + k], c * v);
}

// Register-accumulated segment sum over sorted `batch`.
constexpr int POOL_NPB = 512;  // nodes per block
__global__ __launch_bounds__(256) void pool_k(
    const float* __restrict__ h, const int* __restrict__ batch,
    float* __restrict__ gsum, float* __restrict__ cnt, int N)
{
    int k = threadIdx.x & 31;
    int row = threadIdx.x >> 5;  // 0..7
    int start = blockIdx.x * POOL_NPB;
    int end = min(start + POOL_NPB, N);
    int curg = -1;
    float acc = 0.f, cacc = 0.f;
    for (int n = start + row; n < end; n += 8) {
        int g = batch[n];
        float v = h[(size_t)n * Dk + k];
        if (g != curg) {
            if (curg >= 0) {
                unsafeAtomicAdd(&gsum[curg * Dk + k], acc);
                if (k == 0) unsafeAtomicAdd(&cnt[curg], cacc);
            }
            curg = g; acc = 0.f; cacc = 0.f;
        }
        acc += v; cacc += 1.f;
    }
    if (curg >= 0) {
        unsafeAtomicAdd(&gsum[curg * Dk + k], acc);
        if (k == 0) unsafeAtomicAdd(&cnt[curg], cacc);
    }
}

__global__ __launch_bounds__(64) void final_k(
    const float* __restrict__ gsum, const float* __restrict__ cnt,
    const float* __restrict__ Wdec,   // [32,4]
    const float* __restrict__ orient, // [G,2]
    float* __restrict__ out, int G)
{
    int g = blockIdx.x * blockDim.x + threadIdx.x;
    if (g >= G) return;
    float ic = 1.f / fmaxf(cnt[g], 1.f);
    float c0 = 0.f, c1 = 0.f, c2 = 0.f, c3 = 0.f;
#pragma unroll
    for (int i = 0; i < Dk; i++) {
        float gv = gsum[g * Dk + i] * ic;
        c0 += gv * Wdec[i * 4 + 0];
        c1 += gv * Wdec[i * 4 + 1];
        c2 += gv * Wdec[i * 4 + 2];
        c3 += gv * Wdec[i * 4 + 3];
    }
    float th = orient[g * 2 + 0], ph = orient[g * 2 + 1];
    float st = sinf(th), ct = cosf(th), sp = sinf(ph), cp = cosf(ph);
    float qx = st * cp, qy = st * sp, qz = ct;
    const float S3 = 1.7320508075688772f;
    out[g] = c0 + c1 * S3 * qy + c2 * S3 * qz + c3 * S3 * qx;
}

extern "C" void kernel_launch(void* const* d_in, const int* in_sizes, int n_in,
                              void* d_out, int out_size, void* d_ws, size_t ws_size,
                              hipStream_t stream) {
    const float* pos     = (const float*)d_in[0];
    const float* x       = (const float*)d_in[1];
    const float* orient  = (const float*)d_in[2];
    const float* W_embed = (const float*)d_in[3];
    const float* W_tp    = (const float*)d_in[4];
    const float* W_fc1   = (const float*)d_in[5];
    const float* W_fc2   = (const float*)d_in[6];
    const float* W_dec   = (const float*)d_in[7];
    const int*   esrc    = (const int*)d_in[8];
    const int*   edst    = (const int*)d_in[9];
    const int*   batch   = (const int*)d_in[10];

    const int N = in_sizes[0] / 3;
    const int E = in_sizes[8];
    const int G = in_sizes[2] / 2;

    // ws layout (floats): attr[4E] | cfac[3E] | h[32N] | Hp[128N] | gsum[32G] | cnt[G] | rtab[3*(TAB+1)]
    float*  ws   = (float*)d_ws;
    float4* attr = (float4*)ws;
    float*  cfac = ws + (size_t)4 * E;
    float*  h    = cfac + (size_t)3 * E;
    float*  Hp   = h + (size_t)Dk * N;
    float*  gsum = Hp + (size_t)128 * N;
    float*  cnt  = gsum + (size_t)Dk * G;
    float*  rtab = cnt + G;

    hipMemsetAsync(gsum, 0, (size_t)(Dk * G + G) * sizeof(float), stream);

    {
        dim3 grid((TAB + 1 + 255) / 256, Lk);
        radial_tab_k<<<grid, 256, 0, stream>>>(W_fc1, W_fc2, rtab);
    }
    edge_pre<<<(E + 255) / 256, 256, 0, stream>>>(pos, esrc, edst, rtab, attr, cfac, E);
    embed_k<<<(N * 32 + 255) / 256, 256, 0, stream>>>(x, W_embed, h, N);

    for (int l = 0; l < Lk; l++) {
        tp_gemm<<<(N * 32 + 255) / 256, 256, 0, stream>>>(
            h, W_tp + (size_t)l * Dk * Ak * Dk, Hp, N);
        edge_scatter<<<(int)(((size_t)E * 32 + 255) / 256), 256, 0, stream>>>(
            Hp, attr, cfac + (size_t)l * E, esrc, edst, h, E);
    }

    pool_k<<<(N + POOL_NPB - 1) / POOL_NPB, 256, 0, stream>>>(h, batch, gsum, cnt, N);
    final_k<<<(G + 63) / 64, 64, 0, stream>>>(gsum, cnt, W_dec, orient, (float*)d_out, G);
}